// Round 1
// baseline (576.906 us; speedup 1.0000x reference)
//
#include <hip/hip_runtime.h>
#include <hip/hip_bf16.h>

// Problem constants
#define BSZ   8192
#define DIN   4096
#define RNK   2048
#define UNT   4096

typedef __attribute__((ext_vector_type(4))) float  f32x4;
typedef __attribute__((ext_vector_type(8))) float  f32x8;
typedef __attribute__((ext_vector_type(8))) short  s16x8;
typedef __attribute__((ext_vector_type(8))) unsigned short u16x8;

typedef unsigned short u16;

__device__ __forceinline__ u16 f2bf(float f) {
    unsigned int u = __builtin_bit_cast(unsigned int, f);
    // round-to-nearest-even (finite inputs only)
    return (u16)((u + 0x7fffu + ((u >> 16) & 1u)) >> 16);
}

// ---------------- fp32 -> bf16 elementwise convert (8 elems/thread) -------
__global__ void cvt_bf16_kernel(const float* __restrict__ x,
                                u16* __restrict__ y, int n8) {
    int i = blockIdx.x * blockDim.x + threadIdx.x;
    if (i >= n8) return;
    f32x8 v = ((const f32x8*)x)[i];
    u16x8 o;
#pragma unroll
    for (int j = 0; j < 8; ++j) o[j] = f2bf(v[j]);
    ((u16x8*)y)[i] = o;
}

// ------------- U transpose + fold S:  Ut[r][k] = bf16(U[k][r] * S[r]) -----
__global__ void transpose_scale_kernel(const float* __restrict__ U,
                                       const float* __restrict__ S,
                                       u16* __restrict__ Ut) {
    __shared__ float tile[32][33];
    const int r0 = blockIdx.x * 32;   // RANK tile
    const int k0 = blockIdx.y * 32;   // D_IN tile
    const int tx = threadIdx.x;       // 0..31
    const int ty = threadIdx.y;       // 0..7
#pragma unroll
    for (int i = 0; i < 32; i += 8)
        tile[ty + i][tx] = U[(size_t)(k0 + ty + i) * RNK + r0 + tx];
    __syncthreads();
#pragma unroll
    for (int i = 0; i < 32; i += 8) {
        int r = r0 + ty + i;
        Ut[(size_t)r * DIN + k0 + tx] = f2bf(tile[tx][ty + i] * S[r]);
    }
}

// ---------------- async global->LDS, 16B per lane -------------------------
__device__ __forceinline__ void glds16(const void* g, void* l) {
    __builtin_amdgcn_global_load_lds(
        (const __attribute__((address_space(1))) unsigned int*)g,
        (__attribute__((address_space(3))) unsigned int*)l,
        16, 0, 0);
}

// ===========================================================================
// 256x256 tile, BK=64, 8-wave (2Mx4N), 8-phase-per-2-K-tiles schedule.
// C = A @ B^T.  A: [M][K] bf16 bits, Bt: [N][K] bf16 bits.
//
// LDS: double-buffered A(256x64) + B(256x64) bf16 = 128 KiB, LINEAR layout
// (global_load_lds needs lane-contiguous dest). Bank-conflict-free ds_read
// via source-side swizzle: the global column block staged into linear LDS
// block b of row r is (b ^ (r&7)); readers XOR the same way (involution).
//
// Per K-tile T (4 phases = 4 C-quadrants x K=64, 16 MFMA each):
//   ph0: read A[M0-half]+B[N0-slice]; stage B(T+1) half0 -> other buf
//   ph1: read A[M1-half];             stage B(T+1) half1 -> other buf
//   ph2: read B[N1-slice];            stage A(T+2) half0 -> CURRENT buf
//        (safe: all A reads of tile T completed before ph1's end barrier)
//   ph3: no reads;                    stage A(T+2) half1 -> CURRENT buf
//        then s_waitcnt vmcnt(4)  (leaves exactly A(T+2) in flight across
//        the barrier -> loads never drain to 0 in steady state)
// Each phase: {reads|stage} -> s_barrier -> lgkmcnt(0) -> setprio(1) ->
// 16 MFMA -> setprio(0) -> s_barrier.   Raw s_barrier (no implicit vmcnt
// drain); visibility of staged tiles is governed solely by the counted
// vmcnt waits, which is the whole point (T3+T4).
// ===========================================================================
template <int K, bool RELU_BIAS>
__global__ __launch_bounds__(512) void gemm256(
    const u16* __restrict__ A, const u16* __restrict__ Bt,
    void* __restrict__ C, const float* __restrict__ bias, int N) {
    __shared__ u16 As[2][256 * 64];
    __shared__ u16 Bs[2][256 * 64];

    const int t = threadIdx.x;

    // T1: XCD-aware block swizzle (nwg % 8 == 0 for both our grids)
    const int gx = gridDim.x;
    const int nwg = gx * gridDim.y;
    int bid = blockIdx.y * gx + blockIdx.x;
    bid = (bid & 7) * (nwg >> 3) + (bid >> 3);
    const int rowBase = (bid / gx) * 256;
    const int colBase = (bid % gx) * 256;

    // ---- staging addressing: one STG = one 128x64 half-tile = 2 glds/thread
    // thread t covers LDS row (chunkBase + t>>3), block t&7 (16B blocks).
    // Source column is pre-swizzled so the linear LDS slot holds swizzled data.
    const int sRow = t >> 3;                            // 0..63
    const int sCol = ((t & 7) ^ (sRow & 7)) << 3;       // elements (x8 bf16)
    const u16* aS = A  + (size_t)(rowBase + sRow) * K + sCol;
    const u16* bS = Bt + (size_t)(colBase + sRow) * K + sCol;

#define STG(SRC, DST, h_, Tk_, b_) do {                                       \
    const u16* s_ = (SRC) + (size_t)(h_) * 128 * K + (size_t)(Tk_) * 64;      \
    glds16(s_,                  &DST[b_][(h_) * 8192 + t * 8]);               \
    glds16(s_ + (size_t)64 * K, &DST[b_][(h_) * 8192 + 4096 + t * 8]);        \
} while (0)

    // ---- fragment read addressing (16x16x32 MFMA)
    const int lane = t & 63;
    const int wave = t >> 6;
    const int wm = wave >> 2;          // 0..1  (128 rows each)
    const int wn = wave & 3;           // 0..3  (64 cols each)
    const int lr = lane & 15;
    const int lg = lane >> 4;          // 0..3
    const int r7 = lr & 7;
    const int swz0 = ((lg    ) ^ r7) << 4;   // kk=0 byte col (block lg)
    const int swz1 = ((lg + 4) ^ r7) << 4;   // kk=1 byte col (block lg+4)
    const int aRowB = (wm * 128 + lr) * 128; // byte offset of frag row
    const int bRowB = (wn * 64  + lr) * 128;

    f32x4 acc[8][4] = {};
    s16x8 af[8][2], bf[2][2];

    // ---- prologue: tile0 A+B, tile1 A (6 half-tiles = 12 loads/wave)
    STG(aS, As, 0, 0, 0); STG(aS, As, 1, 0, 0);
    STG(bS, Bs, 0, 0, 0); STG(bS, Bs, 1, 0, 0);
    STG(aS, As, 0, 1, 1); STG(aS, As, 1, 1, 1);
    asm volatile("s_waitcnt vmcnt(4)" ::: "memory");   // tile0 ready; tile1:A in flight
    __builtin_amdgcn_s_barrier();

    const int NT = K / 64;
    for (int T = 0; T < NT; ++T) {
        const int cur = T & 1, nxt = cur ^ 1;
        const char* aP = (const char*)&As[cur][0] + aRowB;
        const char* bP = (const char*)&Bs[cur][0] + bRowB;

        // ================= phase 0: quadrant (M0, N0) =================
#pragma unroll
        for (int mi = 0; mi < 4; ++mi) {
            af[mi][0] = *(const s16x8*)(aP + mi * 2048 + swz0);
            af[mi][1] = *(const s16x8*)(aP + mi * 2048 + swz1);
        }
#pragma unroll
        for (int nj = 0; nj < 2; ++nj) {
            bf[nj][0] = *(const s16x8*)(bP + nj * 2048 + swz0);
            bf[nj][1] = *(const s16x8*)(bP + nj * 2048 + swz1);
        }
        if (T + 1 < NT) STG(bS, Bs, 0, T + 1, nxt);
        asm volatile("" ::: "memory");
        __builtin_amdgcn_s_barrier();
        asm volatile("s_waitcnt lgkmcnt(0)" ::: "memory");
        __builtin_amdgcn_sched_barrier(0);
        __builtin_amdgcn_s_setprio(1);
#pragma unroll
        for (int mi = 0; mi < 4; ++mi)
#pragma unroll
            for (int nj = 0; nj < 2; ++nj)
#pragma unroll
                for (int kk = 0; kk < 2; ++kk)
                    acc[mi][nj] = __builtin_amdgcn_mfma_f32_16x16x32_bf16(
                        af[mi][kk], bf[nj][kk], acc[mi][nj], 0, 0, 0);
        __builtin_amdgcn_s_setprio(0);
        asm volatile("" ::: "memory");
        __builtin_amdgcn_s_barrier();

        // ================= phase 1: quadrant (M1, N0) =================
#pragma unroll
        for (int mi = 0; mi < 4; ++mi) {
            af[4 + mi][0] = *(const s16x8*)(aP + (4 + mi) * 2048 + swz0);
            af[4 + mi][1] = *(const s16x8*)(aP + (4 + mi) * 2048 + swz1);
        }
        if (T + 1 < NT) STG(bS, Bs, 1, T + 1, nxt);
        asm volatile("" ::: "memory");
        __builtin_amdgcn_s_barrier();
        asm volatile("s_waitcnt lgkmcnt(0)" ::: "memory");
        __builtin_amdgcn_sched_barrier(0);
        __builtin_amdgcn_s_setprio(1);
#pragma unroll
        for (int mi = 0; mi < 4; ++mi)
#pragma unroll
            for (int nj = 0; nj < 2; ++nj)
#pragma unroll
                for (int kk = 0; kk < 2; ++kk)
                    acc[4 + mi][nj] = __builtin_amdgcn_mfma_f32_16x16x32_bf16(
                        af[4 + mi][kk], bf[nj][kk], acc[4 + mi][nj], 0, 0, 0);
        __builtin_amdgcn_s_setprio(0);
        asm volatile("" ::: "memory");
        __builtin_amdgcn_s_barrier();

        // ================= phase 2: quadrant (M0, N1) =================
#pragma unroll
        for (int nj = 0; nj < 2; ++nj) {
            bf[nj][0] = *(const s16x8*)(bP + (2 + nj) * 2048 + swz0);
            bf[nj][1] = *(const s16x8*)(bP + (2 + nj) * 2048 + swz1);
        }
        if (T + 2 < NT) STG(aS, As, 0, T + 2, cur);   // current-buf A-lo: all A reads done
        asm volatile("" ::: "memory");
        __builtin_amdgcn_s_barrier();
        asm volatile("s_waitcnt lgkmcnt(0)" ::: "memory");
        __builtin_amdgcn_sched_barrier(0);
        __builtin_amdgcn_s_setprio(1);
#pragma unroll
        for (int mi = 0; mi < 4; ++mi)
#pragma unroll
            for (int nj = 0; nj < 2; ++nj)
#pragma unroll
                for (int kk = 0; kk < 2; ++kk)
                    acc[mi][2 + nj] = __builtin_amdgcn_mfma_f32_16x16x32_bf16(
                        af[mi][kk], bf[nj][kk], acc[mi][2 + nj], 0, 0, 0);
        __builtin_amdgcn_s_setprio(0);
        asm volatile("" ::: "memory");
        __builtin_amdgcn_s_barrier();

        // ================= phase 3: quadrant (M1, N1) =================
        if (T + 2 < NT) STG(aS, As, 1, T + 2, cur);   // current-buf A-hi
        asm volatile("" ::: "memory");
        __builtin_amdgcn_s_barrier();
        __builtin_amdgcn_s_setprio(1);
#pragma unroll
        for (int mi = 0; mi < 4; ++mi)
#pragma unroll
            for (int nj = 0; nj < 2; ++nj)
#pragma unroll
                for (int kk = 0; kk < 2; ++kk)
                    acc[4 + mi][2 + nj] = __builtin_amdgcn_mfma_f32_16x16x32_bf16(
                        af[4 + mi][kk], bf[nj][kk], acc[4 + mi][2 + nj], 0, 0, 0);
        __builtin_amdgcn_s_setprio(0);
        // ---- K-tile boundary: counted drain (never 0 in steady state).
        // Outstanding (oldest->newest): T+1:A (4), T+1:B (4), T+2:A (4).
        // vmcnt(4) completes all of tile T+1; leaves T+2:A in flight.
        if (T + 2 < NT) {
            asm volatile("s_waitcnt vmcnt(4)" ::: "memory");
        } else if (T + 1 < NT) {
            asm volatile("s_waitcnt vmcnt(0)" ::: "memory");  // tail only
        }
        asm volatile("" ::: "memory");
        __builtin_amdgcn_s_barrier();
    }
#undef STG

    // ---- epilogue: C/D layout col = lane&15, row = (lane>>4)*4 + reg
    const int cRow = rowBase + wm * 128 + lg * 4;
    const int cCol = colBase + wn * 64 + lr;
    if (RELU_BIAS) {
        float* Cf = (float*)C;
#pragma unroll
        for (int n = 0; n < 4; ++n) {
            const int col = cCol + n * 16;
            const float bv = bias[col];
#pragma unroll
            for (int m = 0; m < 8; ++m) {
#pragma unroll
                for (int r = 0; r < 4; ++r) {
                    float v = acc[m][n][r] + bv;
                    Cf[(size_t)(cRow + m * 16 + r) * N + col] = v > 0.f ? v : 0.f;
                }
            }
        }
    } else {
        u16* Cb = (u16*)C;
#pragma unroll
        for (int n = 0; n < 4; ++n) {
            const int col = cCol + n * 16;
#pragma unroll
            for (int m = 0; m < 8; ++m) {
#pragma unroll
                for (int r = 0; r < 4; ++r)
                    Cb[(size_t)(cRow + m * 16 + r) * N + col] = f2bf(acc[m][n][r]);
            }
        }
    }
}

extern "C" void kernel_launch(void* const* d_in, const int* in_sizes, int n_in,
                              void* d_out, int out_size, void* d_ws, size_t ws_size,
                              hipStream_t stream) {
    const float* X    = (const float*)d_in[0];   // [B, D_IN]
    const float* U    = (const float*)d_in[1];   // [D_IN, RANK]
    const float* S    = (const float*)d_in[2];   // [RANK]
    const float* V    = (const float*)d_in[3];   // [UNITS, RANK]
    const float* bias = (const float*)d_in[4];   // [UNITS]
    float* out = (float*)d_out;                  // [B, UNITS] fp32

    char* ws = (char*)d_ws;
    u16* Xb  = (u16*)ws;                                  // 8192*4096 bf16 = 64 MB
    u16* Utb = (u16*)(ws + ((size_t)64 << 20));           // 2048*4096 bf16 = 16 MB
    u16* Vb  = (u16*)(ws + ((size_t)80 << 20));           // 4096*2048 bf16 = 16 MB
    u16* Hb  = (u16*)(ws + ((size_t)96 << 20));           // 8192*2048 bf16 = 32 MB

    // 1) convert X -> bf16
    {
        int n8 = (BSZ * DIN) / 8;
        cvt_bf16_kernel<<<n8 / 256, 256, 0, stream>>>(X, Xb, n8);
    }
    // 2) Ut = (U * S)^T in bf16
    {
        dim3 grid(RNK / 32, DIN / 32), block(32, 8);
        transpose_scale_kernel<<<grid, block, 0, stream>>>(U, S, Utb);
    }
    // 3) convert V -> bf16 (already [UNITS][RANK] = B^T layout for GEMM2)
    {
        int n8 = (UNT * RNK) / 8;
        cvt_bf16_kernel<<<n8 / 256, 256, 0, stream>>>(V, Vb, n8);
    }
    // 4) H = X @ (U*S)   [8192 x 2048], K=4096, bf16 out
    {
        dim3 grid(RNK / 256, BSZ / 256);   // (8, 32) = 256 wg, 1/CU
        gemm256<DIN, false><<<grid, 512, 0, stream>>>(Xb, Utb, Hb, nullptr, RNK);
    }
    // 5) out = relu(H @ V^T + bias)   [8192 x 4096], K=2048, fp32 out
    {
        dim3 grid(UNT / 256, BSZ / 256);   // (16, 32) = 512 wg
        gemm256<RNK, true><<<grid, 512, 0, stream>>>(Hb, Vb, out, bias, UNT);
    }
}

// Round 2
// 539.038 us; speedup vs baseline: 1.0703x; 1.0703x over previous
//
#include <hip/hip_runtime.h>
#include <hip/hip_bf16.h>

// Problem constants
#define BSZ   8192
#define DIN   4096
#define RNK   2048
#define UNT   4096

typedef __attribute__((ext_vector_type(4))) float  f32x4;
typedef __attribute__((ext_vector_type(8))) float  f32x8;
typedef __attribute__((ext_vector_type(8))) short  s16x8;
typedef __attribute__((ext_vector_type(8))) unsigned short u16x8;

typedef unsigned short u16;

__device__ __forceinline__ u16 f2bf(float f) {
    unsigned int u = __builtin_bit_cast(unsigned int, f);
    // round-to-nearest-even (finite inputs only)
    return (u16)((u + 0x7fffu + ((u >> 16) & 1u)) >> 16);
}

// ---------------- fp32 -> bf16 elementwise convert (8 elems/thread) -------
__global__ void cvt_bf16_kernel(const float* __restrict__ x,
                                u16* __restrict__ y, int n8) {
    int i = blockIdx.x * blockDim.x + threadIdx.x;
    if (i >= n8) return;
    f32x8 v = ((const f32x8*)x)[i];
    u16x8 o;
#pragma unroll
    for (int j = 0; j < 8; ++j) o[j] = f2bf(v[j]);
    ((u16x8*)y)[i] = o;
}

// ------------- U transpose + fold S:  Ut[r][k] = bf16(U[k][r] * S[r]) -----
__global__ void transpose_scale_kernel(const float* __restrict__ U,
                                       const float* __restrict__ S,
                                       u16* __restrict__ Ut) {
    __shared__ float tile[32][33];
    const int r0 = blockIdx.x * 32;   // RANK tile
    const int k0 = blockIdx.y * 32;   // D_IN tile
    const int tx = threadIdx.x;       // 0..31
    const int ty = threadIdx.y;       // 0..7
#pragma unroll
    for (int i = 0; i < 32; i += 8)
        tile[ty + i][tx] = U[(size_t)(k0 + ty + i) * RNK + r0 + tx];
    __syncthreads();
#pragma unroll
    for (int i = 0; i < 32; i += 8) {
        int r = r0 + ty + i;
        Ut[(size_t)r * DIN + k0 + tx] = f2bf(tile[tx][ty + i] * S[r]);
    }
}

// ---------------- async global->LDS, 16B per lane -------------------------
__device__ __forceinline__ void glds16(const void* g, void* l) {
    __builtin_amdgcn_global_load_lds(
        (const __attribute__((address_space(1))) unsigned int*)g,
        (__attribute__((address_space(3))) unsigned int*)l,
        16, 0, 0);
}

#define LDS_FENCE() asm volatile("" ::: "memory")

// ===========================================================================
// 256x256 tile, BK=64, 8-wave (2Mx4N).  C = A @ B^T.
// A: [M][K] bf16 bits, Bt: [N][K] bf16 bits.
//
// LDS: double-buffered A(256x64) + B(256x64) bf16 = 128 KiB, LINEAR layout
// (global_load_lds needs lane-contiguous dest). Bank-conflict-free ds_read
// via source-side swizzle: global column block staged into linear LDS block
// b of row r is (b ^ (r&7)); readers XOR the same way (involution).
//
// Sync structure (v2): TWO barriers per K-tile, not eight.  Hazards:
//   - A(T+2) staged into As[cur] needs all waves' A-reads of tile T done.
//     All A-reads happen in half-step 1; each wave's reads complete before
//     its half-1 MFMAs (compiler lgkm waits) -> the MID barrier (after
//     half-1 MFMAs) is sufficient.
//   - B(T+1) staged into Bs[nxt] needs tile T-1's B-reads done: guaranteed
//     by the previous BOUNDARY barrier (reads complete before each wave's
//     MFMAs, MFMAs before the barrier).
//   - RAW visibility of staged tiles: counted vmcnt at the boundary
//     (vmcnt(4): completes A(T+1)+B(T+1), leaves A(T+2) in flight -> loads
//     never drain to 0 in steady state) + the boundary barrier.
// Between barriers, waves slip freely: one wave's ds_read/glds traffic runs
// under another wave's MFMAs (setprio(1) favors the MFMA-issuing wave).
// No explicit lgkmcnt drains: reads are plain loads, the compiler emits
// fine-grained lgkmcnt(N) so MFMAs start while later reads are in flight.
// ===========================================================================
template <int K, bool RELU_BIAS>
__global__ __launch_bounds__(512) void gemm256(
    const u16* __restrict__ A, const u16* __restrict__ Bt,
    void* __restrict__ C, const float* __restrict__ bias, int N) {
    __shared__ u16 As[2][256 * 64];
    __shared__ u16 Bs[2][256 * 64];

    const int t = threadIdx.x;

    // T1: XCD-aware block swizzle (nwg % 8 == 0 for both our grids)
    const int gx = gridDim.x;
    const int nwg = gx * gridDim.y;
    int bid = blockIdx.y * gx + blockIdx.x;
    bid = (bid & 7) * (nwg >> 3) + (bid >> 3);
    const int rowBase = (bid / gx) * 256;
    const int colBase = (bid % gx) * 256;

    // ---- staging addressing: one STG = one 128x64 half-tile = 2 glds/thread
    // thread t covers LDS row (chunkBase + t>>3), 16B block t&7.
    // Source column is pre-swizzled so the linear LDS slot holds swizzled data.
    const int sRow = t >> 3;                            // 0..63
    const int sCol = ((t & 7) ^ (sRow & 7)) << 3;       // elements (x8 bf16)
    const u16* aS = A  + (size_t)(rowBase + sRow) * K + sCol;
    const u16* bS = Bt + (size_t)(colBase + sRow) * K + sCol;

#define STG(SRC, DST, h_, Tk_, b_) do {                                       \
    const u16* s_ = (SRC) + (size_t)(h_) * 128 * K + (size_t)(Tk_) * 64;      \
    glds16(s_,                  &DST[b_][(h_) * 8192 + t * 8]);               \
    glds16(s_ + (size_t)64 * K, &DST[b_][(h_) * 8192 + 4096 + t * 8]);        \
} while (0)

    // ---- fragment read addressing (16x16x32 MFMA)
    const int lane = t & 63;
    const int wave = t >> 6;
    const int wm = wave >> 2;          // 0..1  (128 rows each)
    const int wn = wave & 3;           // 0..3  (64 cols each)
    const int lr = lane & 15;
    const int lg = lane >> 4;          // 0..3
    const int r7 = lr & 7;
    const int swz0 = ((lg    ) ^ r7) << 4;   // kk=0 byte col (block lg)
    const int swz1 = ((lg + 4) ^ r7) << 4;   // kk=1 byte col (block lg+4)
    const int aRowB = (wm * 128 + lr) * 128; // byte offset of frag row
    const int bRowB = (wn * 64  + lr) * 128;

    f32x4 acc[8][4] = {};
    s16x8 af[8][2], bf[2][2];

    // ---- prologue: tile0 A+B, tile1 A (6 half-tiles = 12 loads/thread)
    STG(aS, As, 0, 0, 0); STG(aS, As, 1, 0, 0);
    STG(bS, Bs, 0, 0, 0); STG(bS, Bs, 1, 0, 0);
    STG(aS, As, 0, 1, 1); STG(aS, As, 1, 1, 1);
    asm volatile("s_waitcnt vmcnt(4)" ::: "memory");   // tile0 ready; tile1:A in flight
    LDS_FENCE();
    __builtin_amdgcn_s_barrier();
    LDS_FENCE();

    const int NT = K / 64;
    for (int T = 0; T < NT; ++T) {
        const int cur = T & 1, nxt = cur ^ 1;
        const char* aP = (const char*)&As[cur][0] + aRowB;
        const char* bP = (const char*)&Bs[cur][0] + bRowB;

        // ============ half-step 1: acc cols 0..31 (nj=0,1), all 8 M-frags
        if (T + 1 < NT) { STG(bS, Bs, 0, T + 1, nxt); STG(bS, Bs, 1, T + 1, nxt); }
#pragma unroll
        for (int mi = 0; mi < 8; ++mi) {
            af[mi][0] = *(const s16x8*)(aP + mi * 2048 + swz0);
            af[mi][1] = *(const s16x8*)(aP + mi * 2048 + swz1);
        }
#pragma unroll
        for (int nj = 0; nj < 2; ++nj) {
            bf[nj][0] = *(const s16x8*)(bP + nj * 2048 + swz0);
            bf[nj][1] = *(const s16x8*)(bP + nj * 2048 + swz1);
        }
        __builtin_amdgcn_s_setprio(1);
#pragma unroll
        for (int kk = 0; kk < 2; ++kk)          // kk outer: dependent pairs 16 apart
#pragma unroll
            for (int mi = 0; mi < 8; ++mi)
#pragma unroll
                for (int nj = 0; nj < 2; ++nj)
                    acc[mi][nj] = __builtin_amdgcn_mfma_f32_16x16x32_bf16(
                        af[mi][kk], bf[nj][kk], acc[mi][nj], 0, 0, 0);
        __builtin_amdgcn_s_setprio(0);
        // MID barrier: after it, every wave's A-reads of tile T are complete
        LDS_FENCE();
        __builtin_amdgcn_s_barrier();
        LDS_FENCE();

        // ============ half-step 2: acc cols 32..63 (nj=2,3)
        if (T + 2 < NT) { STG(aS, As, 0, T + 2, cur); STG(aS, As, 1, T + 2, cur); }
#pragma unroll
        for (int nj = 0; nj < 2; ++nj) {
            bf[nj][0] = *(const s16x8*)(bP + (2 + nj) * 2048 + swz0);
            bf[nj][1] = *(const s16x8*)(bP + (2 + nj) * 2048 + swz1);
        }
        __builtin_amdgcn_s_setprio(1);
#pragma unroll
        for (int kk = 0; kk < 2; ++kk)
#pragma unroll
            for (int mi = 0; mi < 8; ++mi)
#pragma unroll
                for (int nj = 0; nj < 2; ++nj)
                    acc[mi][2 + nj] = __builtin_amdgcn_mfma_f32_16x16x32_bf16(
                        af[mi][kk], bf[nj][kk], acc[mi][2 + nj], 0, 0, 0);
        __builtin_amdgcn_s_setprio(0);
        // ---- K-tile boundary: counted drain (never 0 in steady state).
        // Outstanding (oldest->newest): A(T+1) 4, B(T+1) 4, A(T+2) 4.
        // vmcnt(4) completes tile T+1's A and B; leaves A(T+2) in flight.
        if (T + 2 < NT) {
            asm volatile("s_waitcnt vmcnt(4)" ::: "memory");
        } else if (T + 1 < NT) {
            asm volatile("s_waitcnt vmcnt(0)" ::: "memory");  // tail only
        }
        LDS_FENCE();
        __builtin_amdgcn_s_barrier();
        LDS_FENCE();
    }
#undef STG

    // ---- epilogue: C/D layout col = lane&15, row = (lane>>4)*4 + reg
    const int cRow = rowBase + wm * 128 + lg * 4;
    const int cCol = colBase + wn * 64 + lr;
    if (RELU_BIAS) {
        float* Cf = (float*)C;
#pragma unroll
        for (int n = 0; n < 4; ++n) {
            const int col = cCol + n * 16;
            const float bv = bias[col];
#pragma unroll
            for (int m = 0; m < 8; ++m) {
#pragma unroll
                for (int r = 0; r < 4; ++r) {
                    float v = acc[m][n][r] + bv;
                    Cf[(size_t)(cRow + m * 16 + r) * N + col] = v > 0.f ? v : 0.f;
                }
            }
        }
    } else {
        u16* Cb = (u16*)C;
#pragma unroll
        for (int n = 0; n < 4; ++n) {
            const int col = cCol + n * 16;
#pragma unroll
            for (int m = 0; m < 8; ++m) {
#pragma unroll
                for (int r = 0; r < 4; ++r)
                    Cb[(size_t)(cRow + m * 16 + r) * N + col] = f2bf(acc[m][n][r]);
            }
        }
    }
}

extern "C" void kernel_launch(void* const* d_in, const int* in_sizes, int n_in,
                              void* d_out, int out_size, void* d_ws, size_t ws_size,
                              hipStream_t stream) {
    const float* X    = (const float*)d_in[0];   // [B, D_IN]
    const float* U    = (const float*)d_in[1];   // [D_IN, RANK]
    const float* S    = (const float*)d_in[2];   // [RANK]
    const float* V    = (const float*)d_in[3];   // [UNITS, RANK]
    const float* bias = (const float*)d_in[4];   // [UNITS]
    float* out = (float*)d_out;                  // [B, UNITS] fp32

    char* ws = (char*)d_ws;
    u16* Xb  = (u16*)ws;                                  // 8192*4096 bf16 = 64 MB
    u16* Utb = (u16*)(ws + ((size_t)64 << 20));           // 2048*4096 bf16 = 16 MB
    u16* Vb  = (u16*)(ws + ((size_t)80 << 20));           // 4096*2048 bf16 = 16 MB
    u16* Hb  = (u16*)(ws + ((size_t)96 << 20));           // 8192*2048 bf16 = 32 MB

    // 1) convert X -> bf16
    {
        int n8 = (BSZ * DIN) / 8;
        cvt_bf16_kernel<<<n8 / 256, 256, 0, stream>>>(X, Xb, n8);
    }
    // 2) Ut = (U * S)^T in bf16
    {
        dim3 grid(RNK / 32, DIN / 32), block(32, 8);
        transpose_scale_kernel<<<grid, block, 0, stream>>>(U, S, Utb);
    }
    // 3) convert V -> bf16 (already [UNITS][RANK] = B^T layout for GEMM2)
    {
        int n8 = (UNT * RNK) / 8;
        cvt_bf16_kernel<<<n8 / 256, 256, 0, stream>>>(V, Vb, n8);
    }
    // 4) H = X @ (U*S)   [8192 x 2048], K=4096, bf16 out
    {
        dim3 grid(RNK / 256, BSZ / 256);   // (8, 32) = 256 wg, 1/CU
        gemm256<DIN, false><<<grid, 512, 0, stream>>>(Xb, Utb, Hb, nullptr, RNK);
    }
    // 5) out = relu(H @ V^T + bias)   [8192 x 4096], K=2048, fp32 out
    {
        dim3 grid(UNT / 256, BSZ / 256);   // (16, 32) = 512 wg
        gemm256<RNK, true><<<grid, 512, 0, stream>>>(Hb, Vb, out, bias, UNT);
    }
}